// Round 10
// baseline (127.731 us; speedup 1.0000x reference)
//
#include <hip/hip_runtime.h>
#include <hip/hip_fp16.h>
#include <math.h>

#define NN 5000      // nodes
#define GG 16        // graphs (B*D)
#define VV 256       // vocab
#define FF 64        // in channels
#define HH 4         // heads
#define CC 32        // channels/head
#define HC 128       // H*C
#define EE 80000     // edges before self loops
#define NEG 0.2f
#define CAP 96       // bucket capacity per node (1 + max in-degree ~46 for this E/N)

// ---------------------------------------------------------------------------
// Kernel 1 (R8-proven, verbatim): blocks 0..VV-1 build T16 row v and
// as_t[v], ad_t[v]; tail blocks init bucket: cursor[n]=1, self-loop slot 0.
// ---------------------------------------------------------------------------
__global__ void k_tables(const float* __restrict__ emb, const float* __restrict__ W,
                         const float* __restrict__ att_src, const float* __restrict__ att_dst,
                         __half* __restrict__ T16, float* __restrict__ as_t,
                         float* __restrict__ ad_t,
                         int* __restrict__ cursor, int* __restrict__ csr) {
  if (blockIdx.x >= VV) {
    int n = (blockIdx.x - VV) * 128 + threadIdx.x;
    if (n < NN) {
      cursor[n] = 1;        // slot 0 taken by self loop
      csr[n * CAP] = n;     // self-loop entry
    }
    return;
  }
  __shared__ float se[FF];
  __shared__ float sT[HC];
  const int v = blockIdx.x;
  const int k = threadIdx.x;          // 0..127
  if (k < FF) se[k] = emb[v * FF + k];
  __syncthreads();
  float acc = 0.f;
#pragma unroll
  for (int f = 0; f < FF; ++f) acc += se[f] * W[f * HC + k];
  T16[v * HC + k] = __float2half(acc);
  sT[k] = acc;
  __syncthreads();
  if (k < 2 * HH) {
    const int h = k >> 1;
    const float* att = (k & 1) ? att_dst : att_src;
    float s = 0.f;
#pragma unroll
    for (int c = 0; c < CC; ++c) s += sT[h * CC + c] * att[h * CC + c];
    if (k & 1) ad_t[v * HH + h] = s;
    else       as_t[v * HH + h] = s;
  }
}

// ---------------------------------------------------------------------------
// Kernel 2 (R9-proven, verbatim): scatter into buckets + P table +
// x-transpose xT[n][g] = x[g][n].
// ---------------------------------------------------------------------------
#define NSCAT ((EE + 255) / 256)
#define NXT   ((GG * NN + 255) / 256)
__global__ void k_scatter_p(const int* __restrict__ src, const int* __restrict__ dst,
                            int* __restrict__ cursor, int* __restrict__ csr,
                            const float* __restrict__ as_t, const float* __restrict__ ad_t,
                            float* __restrict__ P,
                            const int* __restrict__ x, int* __restrict__ xT) {
  if (blockIdx.x < NSCAT) {
    int e = blockIdx.x * 256 + threadIdx.x;
    if (e < EE) {
      int d = dst[e];
      int pos = atomicAdd(&cursor[d], 1);
      if (pos < CAP) csr[d * CAP + pos] = src[e];
    }
    return;
  }
  if (blockIdx.x < NSCAT + VV) {
    const int d = blockIdx.x - NSCAT;   // 0..255
    const int v = threadIdx.x;          // 0..255
    const float4 a = ((const float4*)as_t)[v];
    const float4 b = ((const float4*)ad_t)[d];
    float e0 = a.x + b.x; e0 = e0 > 0.f ? e0 : NEG * e0;
    float e1 = a.y + b.y; e1 = e1 > 0.f ? e1 : NEG * e1;
    float e2 = a.z + b.z; e2 = e2 > 0.f ? e2 : NEG * e2;
    float e3 = a.w + b.w; e3 = e3 > 0.f ? e3 : NEG * e3;
    float4 p;
    p.x = __expf(e0); p.y = __expf(e1); p.z = __expf(e2); p.w = __expf(e3);
    ((float4*)P)[d * VV + v] = p;
    return;
  }
  // x-transpose: xT[n*16+g] = x[g*NN+n]
  const int i = (blockIdx.x - NSCAT - VV) * 256 + threadIdx.x;
  if (i < GG * NN) {
    const int n = i >> 4, g = i & 15;
    xT[i] = x[g * NN + n];
  }
}

// ---------------------------------------------------------------------------
// Main kernel: one block per node, g = tid>>4, 16 lanes per graph, 8 ch/lane.
// Per 16-edge chunk, lane (g,sl) prefetches xv for edge sl of its graph
// (one scattered load per chunk). Per edge: xv via ds_bpermute (register
// crossbar, no global), one float4 P broadcast per graph group (head
// selected in-register), one coalesced uint4 T16 row read. 1-deep chain.
// ---------------------------------------------------------------------------
__global__ __launch_bounds__(256)
void k_gat(const int* __restrict__ xT, const int* __restrict__ cursor,
           const int* __restrict__ csr, const __half* __restrict__ T16,
           const float* __restrict__ P, const float* __restrict__ bias,
           float* __restrict__ out) {
  const int tid  = threadIdx.x;
  const int n    = blockIdx.x;                // node
  const int g    = tid >> 4;                  // graph 0..15
  const int sl   = tid & 15;                  // sub-lane within graph group
  const int hsel = sl >> 2;                   // my 8 channels' head
  const int lane = tid & 63;
  const int g4   = lane & 48;                 // graph-group base within wave

  const int base = n * CAP;
  const int deg  = min(cursor[n], CAP);       // includes self loop (slot 0)
  const int xd   = xT[n * 16 + g];
  const float4* __restrict__ Pd4 = ((const float4*)P) + ((size_t)xd << 8);

  const int d0 = min(deg, 64);
  // coalesced prefetch of csr slots 0..63 (guarded: poison beyond deg)
  const int my_csr = (lane < d0) ? csr[base + lane] : n;

  float4 a_lo = make_float4(0.f, 0.f, 0.f, 0.f);
  float4 a_hi = make_float4(0.f, 0.f, 0.f, 0.f);
  float dsum = 0.f;

  const int nch = (d0 + 15) >> 4;
  for (int c = 0; c < nch; ++c) {
    // chunk prefetch: lane (g,sl) resolves xv for edge (c*16+sl) of graph g
    const int srcn  = __shfl(my_csr, (c << 4) | sl);   // bpermute
    const int my_xv = xT[(srcn << 4) + g];             // scattered, 1/chunk
    const int jmax  = min(16, d0 - (c << 4));
#pragma unroll 4
    for (int j = 0; j < jmax; ++j) {
      const int xv = __shfl(my_xv, g4 | j);            // bpermute, no global
      const float4 p4 = Pd4[xv];                       // 16B broadcast per group
      union { uint4 u; __half2 h2[4]; } tt;
      tt.u = *(const uint4*)&T16[((size_t)xv << 7) + sl * 8];  // 256 B/group
      const float p = (hsel < 2) ? (hsel ? p4.y : p4.x)
                                 : (hsel == 2 ? p4.z : p4.w);
      const float2 f0 = __half22float2(tt.h2[0]);
      const float2 f1 = __half22float2(tt.h2[1]);
      const float2 f2 = __half22float2(tt.h2[2]);
      const float2 f3 = __half22float2(tt.h2[3]);
      a_lo.x += p * f0.x; a_lo.y += p * f0.y; a_lo.z += p * f1.x; a_lo.w += p * f1.y;
      a_hi.x += p * f2.x; a_hi.y += p * f2.y; a_hi.z += p * f3.x; a_hi.w += p * f3.y;
      dsum += p;
    }
  }
  for (int j = 64; j < deg; ++j) {            // rare tail (deg>64 never seen; safe)
    const int srcn = csr[base + j];
    const int xv   = xT[(srcn << 4) + g];
    const float4 p4 = Pd4[xv];
    union { uint4 u; __half2 h2[4]; } tt;
    tt.u = *(const uint4*)&T16[((size_t)xv << 7) + sl * 8];
    const float p = (hsel < 2) ? (hsel ? p4.y : p4.x)
                               : (hsel == 2 ? p4.z : p4.w);
    const float2 f0 = __half22float2(tt.h2[0]);
    const float2 f1 = __half22float2(tt.h2[1]);
    const float2 f2 = __half22float2(tt.h2[2]);
    const float2 f3 = __half22float2(tt.h2[3]);
    a_lo.x += p * f0.x; a_lo.y += p * f0.y; a_lo.z += p * f1.x; a_lo.w += p * f1.y;
    a_hi.x += p * f2.x; a_hi.y += p * f2.y; a_hi.z += p * f3.x; a_hi.w += p * f3.y;
    dsum += p;
  }

  const float r = 1.f / dsum;
  const float4 b_lo = ((const float4*)bias)[sl * 2];
  const float4 b_hi = ((const float4*)bias)[sl * 2 + 1];
  float4 o0, o1;
  o0.x = a_lo.x * r + b_lo.x; o0.y = a_lo.y * r + b_lo.y;
  o0.z = a_lo.z * r + b_lo.z; o0.w = a_lo.w * r + b_lo.w;
  o1.x = a_hi.x * r + b_hi.x; o1.y = a_hi.y * r + b_hi.y;
  o1.z = a_hi.z * r + b_hi.z; o1.w = a_hi.w * r + b_hi.w;
  float* op = out + ((size_t)(g * NN + n)) * HC + sl * 8;
  *(float4*)op = o0;
  *(float4*)(op + 4) = o1;
}

// ---------------------------------------------------------------------------
extern "C" void kernel_launch(void* const* d_in, const int* in_sizes, int n_in,
                              void* d_out, int out_size, void* d_ws, size_t ws_size,
                              hipStream_t stream) {
  const int*   x       = (const int*)d_in[0];      // [G,N]
  const int*   adj     = (const int*)d_in[1];      // [2,E]
  const float* emb     = (const float*)d_in[2];    // [V,F]
  const float* W       = (const float*)d_in[3];    // [F,HC]
  const float* att_src = (const float*)d_in[4];    // [H,C]
  const float* att_dst = (const float*)d_in[5];    // [H,C]
  const float* bias    = (const float*)d_in[6];    // [HC]
  float*       out     = (float*)d_out;

  const int* adj_src = adj;
  const int* adj_dst = adj + EE;

  // workspace carve-up (region sizes multiples of 16 B)
  char* wp = (char*)d_ws;
  __half* T16 = (__half*)wp; wp += (size_t)VV * HC * 2;      // 64 KB
  float* as_t = (float*)wp;  wp += (size_t)VV * HH * 4;      // 4 KB
  float* ad_t = (float*)wp;  wp += (size_t)VV * HH * 4;      // 4 KB
  int* cursor = (int*)wp;    wp += (size_t)NN * 4;           // 20000 B
  int* csr    = (int*)wp;    wp += (size_t)NN * CAP * 4;     // 1.92 MB
  float* P    = (float*)wp;  wp += (size_t)VV * VV * HH * 4; // 1 MB
  int* xT     = (int*)wp;    wp += (size_t)GG * NN * 4;      // 320 KB

  const int initblk = (NN + 127) / 128;                      // 40
  k_tables<<<VV + initblk, 128, 0, stream>>>(emb, W, att_src, att_dst,
                                             T16, as_t, ad_t, cursor, csr);
  k_scatter_p<<<NSCAT + VV + NXT, 256, 0, stream>>>(adj_src, adj_dst, cursor, csr,
                                                    as_t, ad_t, P, x, xT);
  k_gat<<<NN, 256, 0, stream>>>(xT, cursor, csr, T16, P, bias, out);
}